// Round 18
// baseline (17336.282 us; speedup 1.0000x reference)
//
#include <hip/hip_runtime.h>
#include <math.h>

// Problem constants (fixed by the reference)
#define NV 20000
#define NH 512
#define NT 1024
#define NB 32
#define MAXD 64

// LSTM persistent-kernel geometry
#define NGRP 8      // groups (independent batch-row sets); sync domain = 1 group
#define BPG 32      // blocks per group
#define BPB 4       // batch rows per group  (NB / NGRP)
#define UPB 16      // hidden units per block (NH / BPG)
#define NJ 64       // gate rows per block = 4*UPB
#define KTOT 1024   // 2*NH
#define NTH 512
#define KHALF 16    // k elements per thread per half (x-half + h-half = 32)

typedef int v4i __attribute__((ext_vector_type(4)));
typedef int v2i __attribute__((ext_vector_type(2)));

// ws layout: [ path: NV*NH f32 | pairs: 2*NB*512*(val,tag) = 256 KB ]

__global__ void init_kernel(int* __restrict__ pairs) {
  int i = blockIdx.x * blockDim.x + threadIdx.x;
  if (i < 2 * NB * NH * 2)
    __hip_atomic_store(&pairs[i], 0, __ATOMIC_RELAXED, __HIP_MEMORY_SCOPE_SYSTEM);
}

// One block per node: all 256 threads walk the same parent chain (uniform),
// each thread accumulates 2 of the 512 embedding columns (coalesced).
__global__ __launch_bounds__(256)
void path_kernel(const int* __restrict__ parents,
                 const float* __restrict__ weight,
                 const float* __restrict__ emb,
                 float* __restrict__ path) {
  int v = blockIdx.x;
  int h = threadIdx.x;
  float acc0 = 0.f, acc1 = 0.f;
  float w = 1.f;
  int cur = v;
#pragma unroll 1
  for (int d = 0; d < MAXD; ++d) {
    if (cur < 0) break;
    const float* row = emb + (size_t)cur * NH;
    acc0 = fmaf(w, row[h], acc0);
    acc1 = fmaf(w, row[h + 256], acc1);
    w *= weight[cur];
    cur = parents[cur];
  }
  path[(size_t)v * NH + h] = acc0;
  path[(size_t)v * NH + h + 256] = acc1;
}

// f(k) = k + k/32 : +1 dword pad per 32 -> conflict-free LDS columns
__device__ __forceinline__ int fpad(int k) { return k + (k >> 5); }

// Persistent LSTM, R18: fused data+tag exchange, zero producer waits.
// h moves as 8B {val, tag} pairs. Producer (64 gate threads) fire-and-forgets
// one dwordx2/pair -- NO ack vmcnt, NO signal store (two coherent-point RTs
// deleted vs R13). Consumer: waves 0..3 each poll their OWN row's pairs
// (8 pairs = 64B/lane, 4 fused dwordx4 + vmcnt, landed-at-asm-exit) until
// all tags == t -- the detecting load IS the h transfer (detect and load
// fuse into one RT). Per-wave independent exit: no cross-wave coordination,
// no 128-lane pressure (R16 lesson). Poll placed AFTER the x-half GEMM so
// producer store-flight hides under compute. Monotonic tags + complete
// bipartite poll dependency (every block reads every producer's pairs
// every step) make parity-buffer overwrite races impossible. 3 barriers.
__global__ __launch_bounds__(NTH, 1)
void lstm_kernel(const int* __restrict__ ev,
                 const float* __restrict__ path,
                 const float* __restrict__ gate_w,
                 const float* __restrict__ gate_b,
                 int* __restrict__ pairs,    // [2][NB][NH][2] (val,tag)
                 float* __restrict__ out) {  // [3][NT][NB][NH]
  __shared__ float in_s[BPB][KTOT + KTOT / 32];   // [x(t) | h(t)] padded
  __shared__ float p_s[32][NJ * BPB + 1];         // stride 257 -> conflict-free
  __shared__ float zred[NJ * BPB];
  __shared__ float c_s[BPB][UPB];

  const int bid = blockIdx.x;
  const int grp = bid >> 5;   // group = consecutive 32-block range
  const int blk = bid & 31;
  const int b0 = grp * BPB;
  const int u0 = blk * UPB;
  const int tid = threadIdx.x;
  const int wid = tid >> 6;   // wave id 0..7
  const int lane = tid & 63;
  const int jg = tid >> 5;    // 0..15: which 4-row group of gate rows
  const int ks = tid & 31;    // 0..31: which k-slice (16 x-k + 16 h-k)

  // gate_w slice:
  // w[jj][0..15]  = W[j][ks*16 .. +16)          (x half)
  // w[jj][16..31] = W[j][512 + ks*16 .. +16)    (h half)
  float w[4][2 * KHALF];
#pragma unroll
  for (int jj = 0; jj < 4; ++jj) {
    int r = jg * 4 + jj;                        // 0..63: gate*16 + uu
    int j = (r >> 4) * NH + u0 + (r & 15);      // global gate row
    const float* wx = gate_w + (size_t)j * KTOT + ks * KHALF;
    const float* wh = gate_w + (size_t)j * KTOT + NH + ks * KHALF;
#pragma unroll
    for (int kk = 0; kk < KHALF; ++kk) {
      w[jj][kk] = wx[kk];
      w[jj][KHALF + kk] = wh[kk];
    }
  }

  if (tid < BPB * UPB) c_s[tid >> 4][tid & 15] = 0.f;

  // staging maps
  const int sb2 = tid >> 7;          // x-prefetch: row 0..3
  const int off4 = (tid & 127) * 4;  // x-prefetch: 4-float chunk
  const size_t plane = (size_t)NT * NB * NH;

  // pre-stage x(0)
  {
    int e = ev[0 * NB + b0 + sb2];
    float4 v0 = *(const float4*)(path + (size_t)e * NH + off4);
    *(float4*)&in_s[sb2][fpad(off4)] = v0;
  }
  __syncthreads();   // x(0) visible to all waves

#pragma unroll 1
  for (int t = 0; t < NT; ++t) {
    const bool more = (t + 1 < NT);

    // ---- x-half GEMM: k in [ks*16, ks*16+16) (x(t) already staged) ----
    float acc[4][BPB];
#pragma unroll
    for (int jj = 0; jj < 4; ++jj)
#pragma unroll
      for (int bi = 0; bi < BPB; ++bi) acc[jj][bi] = 0.f;
    {
      const int fb = fpad(ks * KHALF);
#pragma unroll
      for (int bi = 0; bi < BPB; ++bi) {
        const float* inp = &in_s[bi][fb];
#pragma unroll
        for (int kk = 0; kk < KHALF; ++kk) {
          float x = inp[kk];
          acc[0][bi] = fmaf(w[0][kk], x, acc[0][bi]);
          acc[1][bi] = fmaf(w[1][kk], x, acc[1][bi]);
          acc[2][bi] = fmaf(w[2][kk], x, acc[2][bi]);
          acc[3][bi] = fmaf(w[3][kk], x, acc[3][bi]);
        }
      }
    }

    // ---- poll+stage h(t): waves 0..3, own row, 8 pairs (64B) per lane ----
    if (wid < BPB) {
      const int* psrc =
          pairs + (((size_t)(t & 1) * NB + (b0 + wid)) * NH + lane * 8) * 2;
      v4i p0, p1, p2, p3;
      for (;;) {
        asm volatile(
            "global_load_dwordx4 %0, %4, off sc0 sc1\n\t"
            "global_load_dwordx4 %1, %4, off offset:16 sc0 sc1\n\t"
            "global_load_dwordx4 %2, %4, off offset:32 sc0 sc1\n\t"
            "global_load_dwordx4 %3, %4, off offset:48 sc0 sc1\n\t"
            "s_waitcnt vmcnt(0)"
            : "=&v"(p0), "=&v"(p1), "=&v"(p2), "=&v"(p3)
            : "v"(psrc)
            : "memory");
        bool ok = (p0[1] == t) & (p0[3] == t) & (p1[1] == t) & (p1[3] == t) &
                  (p2[1] == t) & (p2[3] == t) & (p3[1] == t) & (p3[3] == t);
        if (__ballot(ok) == ~0ull) break;
        __builtin_amdgcn_s_sleep(8);
      }
      float* d = &in_s[wid][fpad(NH + lane * 8)];
      float4 q0, q1;
      q0.x = __int_as_float(p0[0]); q0.y = __int_as_float(p0[2]);
      q0.z = __int_as_float(p1[0]); q0.w = __int_as_float(p1[2]);
      q1.x = __int_as_float(p2[0]); q1.y = __int_as_float(p2[2]);
      q1.z = __int_as_float(p3[0]); q1.w = __int_as_float(p3[2]);
      *(float4*)(d + 0) = q0;
      *(float4*)(d + 4) = q1;
    }
    __syncthreads();   // A1: h(t) staged

    // ---- h-half GEMM: k in [512 + ks*16, +16) ----
    {
      const int fb = fpad(NH + ks * KHALF);
#pragma unroll
      for (int bi = 0; bi < BPB; ++bi) {
        const float* inp = &in_s[bi][fb];
#pragma unroll
        for (int kk = 0; kk < KHALF; ++kk) {
          float x = inp[kk];
          acc[0][bi] = fmaf(w[0][KHALF + kk], x, acc[0][bi]);
          acc[1][bi] = fmaf(w[1][KHALF + kk], x, acc[1][bi]);
          acc[2][bi] = fmaf(w[2][KHALF + kk], x, acc[2][bi]);
          acc[3][bi] = fmaf(w[3][KHALF + kk], x, acc[3][bi]);
        }
      }
    }
#pragma unroll
    for (int jj = 0; jj < 4; ++jj) {
      int r = jg * 4 + jj;
#pragma unroll
      for (int bi = 0; bi < BPB; ++bi)
        p_s[ks][r * BPB + bi] = acc[jj][bi];
    }
    __syncthreads();   // B: p_s complete; in_s x-half dead

    // ---- prefetch x(t+1) into in_s x-half (cached; off critical path) ----
    if (more) {
      int e = ev[(t + 1) * NB + b0 + sb2];
      float4 v0 = *(const float4*)(path + (size_t)e * NH + off4);
      *(float4*)&in_s[sb2][fpad(off4)] = v0;
    }

    // ---- reduce 32 k-slices + bias ----
    if (tid < NJ * BPB) {
      float s = 0.f;
#pragma unroll
      for (int k2 = 0; k2 < 32; ++k2) s += p_s[k2][tid];
      int r = tid >> 2;
      s += gate_b[(r >> 4) * NH + u0 + (r & 15)];
      zred[tid] = s;
    }
    __syncthreads();   // C: zred complete

    // ---- gates + state update + fire-and-forget tagged handoff ----
    if (tid < BPB * UPB) {
      int bi = tid >> 4, uu = tid & 15;
      float zi = zred[(uu) * BPB + bi];
      float zf = zred[(UPB + uu) * BPB + bi];
      float zg = zred[(2 * UPB + uu) * BPB + bi];
      float zo = zred[(3 * UPB + uu) * BPB + bi];
      float ig = 1.f / (1.f + expf(-zi));
      float fg = 1.f / (1.f + expf(-zf));
      float gg = tanhf(zg);
      float ogv = 1.f / (1.f + expf(-zo));
      float cv = fmaf(fg, c_s[bi][uu], ig * gg);
      float hvv = ogv * tanhf(cv);
      c_s[bi][uu] = cv;
      int b = b0 + bi, u = u0 + uu;
      if (more) {
        int* pdst = pairs + (((size_t)((t + 1) & 1) * NB + b) * NH + u) * 2;
        v2i pr;
        pr[0] = __float_as_int(hvv);
        pr[1] = t + 1;
        asm volatile("global_store_dwordx2 %0, %1, off sc0 sc1"
                     :: "v"(pdst), "v"(pr) : "memory");
      }
      // output stores off the critical path (after the handoff)
      size_t o0 = ((size_t)t * NB + b) * NH + u;
      out[o0] = hvv;
      out[plane + o0] = cv;
      out[2 * plane + o0] = ogv;
    }
    // no end-of-step barrier: next iteration's poll + A1 covers it
  }
}

extern "C" void kernel_launch(void* const* d_in, const int* in_sizes, int n_in,
                              void* d_out, int out_size, void* d_ws, size_t ws_size,
                              hipStream_t stream) {
  const int* ev = (const int*)d_in[0];
  const int* parents = (const int*)d_in[1];
  const float* weight = (const float*)d_in[2];
  const float* emb = (const float*)d_in[3];
  const float* gate_w = (const float*)d_in[4];
  const float* gate_b = (const float*)d_in[5];
  float* out = (float*)d_out;

  char* ws = (char*)d_ws;
  float* path = (float*)ws;
  size_t path_bytes = (size_t)NV * NH * sizeof(float);
  int* pairs = (int*)(ws + path_bytes);

  init_kernel<<<(2 * NB * NH * 2 + 255) / 256, 256, 0, stream>>>(pairs);
  path_kernel<<<NV, 256, 0, stream>>>(parents, weight, emb, path);
  lstm_kernel<<<NGRP * BPG, NTH, 0, stream>>>(ev, path, gate_w, gate_b, pairs, out);
}

// Round 19
// 12359.802 us; speedup vs baseline: 1.4026x; 1.4026x over previous
//
#include <hip/hip_runtime.h>
#include <math.h>

// Problem constants (fixed by the reference)
#define NV 20000
#define NH 512
#define NT 1024
#define NB 32
#define MAXD 64

// LSTM persistent-kernel geometry
#define NGRP 8      // groups (independent batch-row sets); sync domain = 1 group
#define BPG 32      // blocks per group
#define BPB 4       // batch rows per group  (NB / NGRP)
#define UPB 16      // hidden units per block (NH / BPG)
#define NJ 64       // gate rows per block = 4*UPB
#define KTOT 1024   // 2*NH
#define NTH 512
#define KHALF 16    // k elements per thread per half (x-half + h-half = 32)

typedef int v4i __attribute__((ext_vector_type(4)));

// ws layout: [ path: NV*NH f32 (40.96MB) | hbuf: NT*NB*NH f32 (67.1MB) |
//              prog: 256 ints ]  ~= 108.1 MB total (requires ws_size >= that)

__global__ void init_kernel(int* __restrict__ prog) {
  int i = blockIdx.x * blockDim.x + threadIdx.x;
  if (i < 256)
    __hip_atomic_store(&prog[i], 0, __ATOMIC_RELAXED, __HIP_MEMORY_SCOPE_SYSTEM);
}

// One block per node: all 256 threads walk the same parent chain (uniform),
// each thread accumulates 2 of the 512 embedding columns (coalesced).
__global__ __launch_bounds__(256)
void path_kernel(const int* __restrict__ parents,
                 const float* __restrict__ weight,
                 const float* __restrict__ emb,
                 float* __restrict__ path) {
  int v = blockIdx.x;
  int h = threadIdx.x;
  float acc0 = 0.f, acc1 = 0.f;
  float w = 1.f;
  int cur = v;
#pragma unroll 1
  for (int d = 0; d < MAXD; ++d) {
    if (cur < 0) break;
    const float* row = emb + (size_t)cur * NH;
    acc0 = fmaf(w, row[h], acc0);
    acc1 = fmaf(w, row[h + 256], acc1);
    w *= weight[cur];
    cur = parents[cur];
  }
  path[(size_t)v * NH + h] = acc0;
  path[(size_t)v * NH + h + 256] = acc1;
}

// f(k) = k + k/32 : +1 dword pad per 32 -> conflict-free LDS columns
__device__ __forceinline__ int fpad(int k) { return k + (k >> 5); }

// Persistent LSTM, R19: WRITE-ONCE h buffers + CACHED consumer reads.
// Model (fits all 18 rounds): every sc0/sc1 bypass request costs a full
// ~128B sector of coherent-point bandwidth; CP path serves ~2 TB/s (observed
// hbm_gbps 1.8-2.3 TB/s in every round). R13's 512 h-load requests/block
// x 256 blocks x 128B ~= 17MB/step / 2TB/s ~= 8.5us = the step time. The
// 32x redundancy (each group's 8KB fetched separately by 32 consumers,
// uncacheable) is the structural cost.
// Fix: hbuf[t] is written once (bypass, before signal) and read only after
// signal -> consumers can use PLAIN CACHED loads; each XCD's L2 fetches
// each line once and serves its local consumers. Intra-launch: write-once +
// signal gating => no staleness. Cross-launch/poison: launch-boundary L2
// writeback+invalidate is proven on this harness (path->lstm cross-XCD
// dataflow has passed 15 rounds). t=0 zero-fills LDS (hbuf needs no init).
// Producer side and poll (8 lanes x dwordx4, sleep(1)) are byte-identical
// to R13.
__global__ __launch_bounds__(NTH, 1)
void lstm_kernel(const int* __restrict__ ev,
                 const float* __restrict__ path,
                 const float* __restrict__ gate_w,
                 const float* __restrict__ gate_b,
                 float* __restrict__ hbuf,   // [NT][NB][NH] write-once per t
                 int* __restrict__ prog,     // [NGRP][BPG] per-producer step ctr
                 float* __restrict__ out) {  // [3][NT][NB][NH]
  __shared__ float in_s[BPB][KTOT + KTOT / 32];   // [x(t) | h(t)] padded
  __shared__ float p_s[32][NJ * BPB + 1];         // stride 257 -> conflict-free
  __shared__ float zred[NJ * BPB];
  __shared__ float c_s[BPB][UPB];

  const int bid = blockIdx.x;
  const int grp = bid & 7;    // R9 decode: if dispatch is round-robin, a
  const int blk = bid >> 3;   // group co-locates on one XCD (perf-only bet;
                              // correctness is placement-free)
  const int b0 = grp * BPB;
  const int u0 = blk * UPB;
  const int tid = threadIdx.x;
  const int jg = tid >> 5;   // 0..15: which 4-row group of gate rows
  const int ks = tid & 31;   // 0..31: which k-slice (16 x-k + 16 h-k)

  // gate_w slice:
  // w[jj][0..15]  = W[j][ks*16 .. +16)          (x half)
  // w[jj][16..31] = W[j][512 + ks*16 .. +16)    (h half)
  float w[4][2 * KHALF];
#pragma unroll
  for (int jj = 0; jj < 4; ++jj) {
    int r = jg * 4 + jj;                        // 0..63: gate*16 + uu
    int j = (r >> 4) * NH + u0 + (r & 15);      // global gate row
    const float* wx = gate_w + (size_t)j * KTOT + ks * KHALF;
    const float* wh = gate_w + (size_t)j * KTOT + NH + ks * KHALF;
#pragma unroll
    for (int kk = 0; kk < KHALF; ++kk) {
      w[jj][kk] = wx[kk];
      w[jj][KHALF + kk] = wh[kk];
    }
  }

  if (tid < BPB * UPB) c_s[tid >> 4][tid & 15] = 0.f;

  // staging map: thread -> (row sb2, 4-float chunk off4)
  const int sb2 = tid >> 7;          // 0..3
  const int off4 = (tid & 127) * 4;  // 0..508
  const size_t plane = (size_t)NT * NB * NH;
  int* myprog = prog + grp * BPG + blk;
  const int* pollp4 = prog + grp * BPG + (tid & 7) * 4;

  // pre-stage x(0) (cached loads; visibility via barrier A1 at t=0)
  {
    int e = ev[0 * NB + b0 + sb2];
    float4 v0 = *(const float4*)(path + (size_t)e * NH + off4);
    *(float4*)&in_s[sb2][fpad(off4)] = v0;
  }

#pragma unroll 1
  for (int t = 0; t < NT; ++t) {
    const bool more = (t + 1 < NT);

    // ---- wait for group's h(t) producers: 8 lanes x dwordx4 (bypass) ----
    if (t > 0 && tid < 8) {
      v4i pv;
      for (;;) {
        asm volatile("global_load_dwordx4 %0, %1, off sc0 sc1\n\ts_waitcnt vmcnt(0)"
                     : "=v"(pv) : "v"(pollp4) : "memory");
        bool ok = (pv[0] >= t) && (pv[1] >= t) && (pv[2] >= t) && (pv[3] >= t);
        if ((__ballot(ok) & 0xFFull) == 0xFFull) break;
        __builtin_amdgcn_s_sleep(1);
      }
    }
    __syncthreads();   // A0: poll passed; prev step's LDS reads all complete

    // ---- stage h(t): PLAIN CACHED loads of write-once hbuf[t] ----
    // (asm "memory" clobber in the poll keeps these from hoisting above it)
    if (t > 0) {
      const float* hsrc = hbuf + ((size_t)t * NB + (b0 + sb2)) * NH + off4;
      float4 hv = *(const float4*)hsrc;
      *(float4*)&in_s[sb2][fpad(NH + off4)] = hv;
    } else {
      float4 z; z.x = 0.f; z.y = 0.f; z.z = 0.f; z.w = 0.f;
      *(float4*)&in_s[sb2][fpad(NH + off4)] = z;
    }
    __syncthreads();   // A1: h(t) staged

    // ---- x-half GEMM: k in [ks*16, ks*16+16) from in_s x-half ----
    float acc[4][BPB];
#pragma unroll
    for (int jj = 0; jj < 4; ++jj)
#pragma unroll
      for (int bi = 0; bi < BPB; ++bi) acc[jj][bi] = 0.f;
    {
      const int fb = fpad(ks * KHALF);
#pragma unroll
      for (int bi = 0; bi < BPB; ++bi) {
        const float* inp = &in_s[bi][fb];
#pragma unroll
        for (int kk = 0; kk < KHALF; ++kk) {
          float x = inp[kk];
          acc[0][bi] = fmaf(w[0][kk], x, acc[0][bi]);
          acc[1][bi] = fmaf(w[1][kk], x, acc[1][bi]);
          acc[2][bi] = fmaf(w[2][kk], x, acc[2][bi]);
          acc[3][bi] = fmaf(w[3][kk], x, acc[3][bi]);
        }
      }
    }

    // ---- h-half GEMM: k in [512 + ks*16, +16) ----
    {
      const int fb = fpad(NH + ks * KHALF);
#pragma unroll
      for (int bi = 0; bi < BPB; ++bi) {
        const float* inp = &in_s[bi][fb];
#pragma unroll
        for (int kk = 0; kk < KHALF; ++kk) {
          float x = inp[kk];
          acc[0][bi] = fmaf(w[0][KHALF + kk], x, acc[0][bi]);
          acc[1][bi] = fmaf(w[1][KHALF + kk], x, acc[1][bi]);
          acc[2][bi] = fmaf(w[2][KHALF + kk], x, acc[2][bi]);
          acc[3][bi] = fmaf(w[3][KHALF + kk], x, acc[3][bi]);
        }
      }
    }
#pragma unroll
    for (int jj = 0; jj < 4; ++jj) {
      int r = jg * 4 + jj;
#pragma unroll
      for (int bi = 0; bi < BPB; ++bi)
        p_s[ks][r * BPB + bi] = acc[jj][bi];
    }
    __syncthreads();   // B: p_s complete; in_s x-half dead

    // ---- prefetch x(t+1) into in_s x-half (cached; off critical path) ----
    if (more) {
      int e = ev[(t + 1) * NB + b0 + sb2];
      float4 v0 = *(const float4*)(path + (size_t)e * NH + off4);
      *(float4*)&in_s[sb2][fpad(off4)] = v0;
    }

    // ---- reduce 32 k-slices + bias ----
    if (tid < NJ * BPB) {
      float s = 0.f;
#pragma unroll
      for (int k2 = 0; k2 < 32; ++k2) s += p_s[k2][tid];
      int r = tid >> 2;
      s += gate_b[(r >> 4) * NH + u0 + (r & 15)];
      zred[tid] = s;
    }
    __syncthreads();   // C: zred complete

    // ---- gates + state update + handoff (wave 0 only) ----
    if (tid < BPB * UPB) {
      int bi = tid >> 4, uu = tid & 15;
      float zi = zred[(uu) * BPB + bi];
      float zf = zred[(UPB + uu) * BPB + bi];
      float zg = zred[(2 * UPB + uu) * BPB + bi];
      float zo = zred[(3 * UPB + uu) * BPB + bi];
      float ig = 1.f / (1.f + expf(-zi));
      float fg = 1.f / (1.f + expf(-zf));
      float gg = tanhf(zg);
      float ogv = 1.f / (1.f + expf(-zo));
      float cv = fmaf(fg, c_s[bi][uu], ig * gg);
      float hvv = ogv * tanhf(cv);
      c_s[bi][uu] = cv;
      int b = b0 + bi, u = u0 + uu;
      if (more) {
        // bypass store to the write-once step buffer (must reach CP before
        // the signal; drained by the vmcnt below)
        float* hdst = hbuf + ((size_t)(t + 1) * NB + b) * NH + u;
        __hip_atomic_store(hdst, hvv, __ATOMIC_RELAXED, __HIP_MEMORY_SCOPE_SYSTEM);
      }
      // announce: wave-level drain of the h stores, then per-producer word
      if (more && tid == 0) {
        asm volatile("s_waitcnt vmcnt(0)" ::: "memory");
        int nv = t + 1;
        asm volatile("global_store_dword %0, %1, off sc0 sc1"
                     :: "v"(myprog), "v"(nv) : "memory");
      }
      // output stores off the critical path (after the signal)
      size_t o0 = ((size_t)t * NB + b) * NH + u;
      out[o0] = hvv;
      out[plane + o0] = cv;
      out[2 * plane + o0] = ogv;
    }
    // no end-of-step barrier: next iteration's poll + A0 covers it
  }
}

extern "C" void kernel_launch(void* const* d_in, const int* in_sizes, int n_in,
                              void* d_out, int out_size, void* d_ws, size_t ws_size,
                              hipStream_t stream) {
  const int* ev = (const int*)d_in[0];
  const int* parents = (const int*)d_in[1];
  const float* weight = (const float*)d_in[2];
  const float* emb = (const float*)d_in[3];
  const float* gate_w = (const float*)d_in[4];
  const float* gate_b = (const float*)d_in[5];
  float* out = (float*)d_out;

  char* ws = (char*)d_ws;
  float* path = (float*)ws;
  size_t path_bytes = (size_t)NV * NH * sizeof(float);
  float* hbuf = (float*)(ws + path_bytes);                 // 67.1 MB
  size_t hbuf_bytes = (size_t)NT * NB * NH * sizeof(float);
  int* prog = (int*)(ws + path_bytes + hbuf_bytes);

  init_kernel<<<1, 256, 0, stream>>>(prog);
  path_kernel<<<NV, 256, 0, stream>>>(parents, weight, emb, path);
  lstm_kernel<<<NGRP * BPG, NTH, 0, stream>>>(ev, path, gate_w, gate_b, hbuf, prog, out);
}